// Round 1
// baseline (6644.002 us; speedup 1.0000x reference)
//
#include <hip/hip_runtime.h>
#include <cmath>

// ============================================================================
// ConvMod1D fused kernel — round 0: correctness-first fp32-compute baseline.
// One block = (batch b, tile of 64 L positions). Halo 12 each side -> 88
// extended positions. All intermediates in LDS as bf16 (RNE), fp32 math.
// 9 reusable slots of 64 rows x 88 cols bf16 (11264 B each) ~= 105 KB LDS.
//
// e-coordinate: e in [0,88) <-> l = l0 + e, l0 = tile*64 - 12.
// Valid ranges per tensor (verified chain):
//   xs0n [0,88)  g1 [0,88)  a1 [3,85)  pv1/t1/mul1 [3,85)  pwv12 [2,86)
//   x1low/x1ln [3,85)  g2 [3,85)  a2 [7,81)  xs2n/pwv22 [6,82)
//   x2low/pv2/t2/mul2/x2ln [7,81)  g3 [7,81)  a3 [12,76)  pv3/t3/mul3 [12,76)
//   xs3n/pwv32 [11,77)  x3/out [12,76)  (out l = tile*64 + [0,64))
// Slot schedule (S0..S8), all conflicts checked phase-by-phase:
//   S0: xs0n -> mul1/x1ln_hi -> mul2_lo/x2ln -> pwv32
//   S1: xs1n -> x1low/x1ln_lo -> mul2_hi/x2ln
//   S2: g1 -> pwv12 -> g2_lo -> xs2n -> pv2_lo/t2_lo -> g3_0/a3_0
//   S3: a1 -> g2_hi -> pwv22 -> pv2_hi/t2_hi -> g3_1/a3_1
//   S4: pv1/t1 -> a2_lo -> g3_2/a3_2
//   S5: a2_hi -> pv3_0/t3_0
//   S6: x2low/x2ln_0 -> xs3n
//   S7: pv3_1/t3_1      S8: pv3_2/t3_2
// ============================================================================

using u16 = unsigned short;

#define DEVI __device__ __forceinline__

static constexpr int EXT   = 88;
static constexpr int SLOT  = 64 * EXT;  // ushorts per slot
static constexpr int NWAVE = 8;         // 512 threads

DEVI u16 f2bf(float f) {                 // round-to-nearest-even bf16
    unsigned u = __float_as_uint(f);
    u += 0x7FFFu + ((u >> 16) & 1u);
    return (u16)(u >> 16);
}
DEVI float bf2f(u16 h) { return __uint_as_float(((unsigned)h) << 16); }
DEVI float gelu_f(float x) { return 0.5f * x * (1.0f + erff(x * 0.70710678118654752f)); }
DEVI int rfl(int v) { return __builtin_amdgcn_readfirstlane(v); }

struct SL { int a, b, c; };

DEVI u16* rowp(u16* sh, SL s, int ch) {
    int sl = ch < 64 ? s.a : (ch < 128 ? s.b : s.c);
    return sh + sl * SLOT + (ch & 63) * EXT;
}

// ---------------- pointwise conv (GEMM over channels), LDS->LDS -------------
template<int O, int C, bool GELU>
DEVI void pw_ph(u16* sh, SL in, SL out, const float* W, const float* bias,
                int elo, int ehi, int l0) {
    const int lane = threadIdx.x & 63;
    const int wv   = threadIdx.x >> 6;
    for (int jb = 0; jb < O / (NWAVE * 4); ++jb) {
        const int o0 = rfl(wv + NWAVE * (4 * jb + 0));
        const int o1 = rfl(wv + NWAVE * (4 * jb + 1));
        const int o2 = rfl(wv + NWAVE * (4 * jb + 2));
        const int o3 = rfl(wv + NWAVE * (4 * jb + 3));
        const float* w0 = W + o0 * C;
        const float* w1 = W + o1 * C;
        const float* w2 = W + o2 * C;
        const float* w3 = W + o3 * C;
        u16* r0 = rowp(sh, out, o0);
        u16* r1 = rowp(sh, out, o1);
        u16* r2 = rowp(sh, out, o2);
        u16* r3 = rowp(sh, out, o3);
        for (int p = elo; p < ehi; p += 64) {
            const int e = p + lane;
            if (e >= ehi) continue;
            float a0 = bias[o0], a1 = bias[o1], a2 = bias[o2], a3 = bias[o3];
            for (int cb = 0; cb < C; cb += 64) {
                const u16* bp = rowp(sh, in, cb) + e;
                const float* q0 = w0 + cb;
                const float* q1 = w1 + cb;
                const float* q2 = w2 + cb;
                const float* q3 = w3 + cb;
                #pragma unroll 16
                for (int c2 = 0; c2 < 64; ++c2) {
                    const float xv = bf2f(bp[c2 * EXT]);
                    a0 = fmaf(q0[c2], xv, a0);
                    a1 = fmaf(q1[c2], xv, a1);
                    a2 = fmaf(q2[c2], xv, a2);
                    a3 = fmaf(q3[c2], xv, a3);
                }
            }
            if (GELU) { a0 = gelu_f(a0); a1 = gelu_f(a1); a2 = gelu_f(a2); a3 = gelu_f(a3); }
            const bool gv = (unsigned)(l0 + e) < 4096u;
            r0[e] = gv ? f2bf(a0) : (u16)0;
            r1[e] = gv ? f2bf(a1) : (u16)0;
            r2[e] = gv ? f2bf(a2) : (u16)0;
            r3[e] = gv ? f2bf(a3) : (u16)0;
        }
    }
}

// ---------------- depthwise conv (row-local), optional add, LDS->LDS --------
// In-place safe when single-pass (width <= 64): all tap reads feed acc before
// the store (dataflow-ordered), rows are owned by a single wave.
template<int C, int K, int PAD, bool ADD>
DEVI void dw_ph(u16* sh, SL in, SL out, SL add, const float* W, const float* bias,
                int elo, int ehi, int l0) {
    const int lane = threadIdx.x & 63;
    const int wv   = threadIdx.x >> 6;
    for (int j = 0; j < C / NWAVE; ++j) {
        const int o = rfl(wv + NWAVE * j);
        const float* wk = W + o * K;
        const u16* ri = rowp(sh, in, o);
        const u16* ra = ADD ? rowp(sh, add, o) : nullptr;
        u16* ro = rowp(sh, out, o);
        const float bo = bias[o];
        for (int p = elo; p < ehi; p += 64) {
            const int e = p + lane;
            if (e >= ehi) continue;
            float acc = bo;
            #pragma unroll
            for (int k = 0; k < K; ++k) acc = fmaf(wk[k], bf2f(ri[e + k - PAD]), acc);
            if (ADD) acc += bf2f(ra[e]);
            const bool gv = (unsigned)(l0 + e) < 4096u;
            ro[e] = gv ? f2bf(acc) : (u16)0;
        }
    }
}

// ---------------- elementwise io *= a ---------------------------------------
template<int C>
DEVI void mul_ph(u16* sh, SL a, SL io, int elo, int ehi) {
    const int lane = threadIdx.x & 63;
    const int wv   = threadIdx.x >> 6;
    for (int j = 0; j < C / NWAVE; ++j) {
        const int o = rfl(wv + NWAVE * j);
        const u16* ra = rowp(sh, a, o);
        u16* r = rowp(sh, io, o);
        for (int p = elo; p < ehi; p += 64) {
            const int e = p + lane;
            if (e < ehi) r[e] = f2bf(bf2f(r[e]) * bf2f(ra[e]));
        }
    }
}

// ---------------- LayerNorm over channels, in place --------------------------
template<int C>
DEVI void ln_ph(u16* sh, SL s, const float* W, const float* bias,
                int elo, int ehi, int l0, float* scr, float* mean, float* rstd) {
    const int tid = threadIdx.x;
    if (tid < 256) {
        const int idx = tid & 127, half = tid >> 7;
        const int e = elo + idx;
        float sm = 0.f, sq = 0.f;
        if (e < ehi) {
            for (int c = half * (C / 2); c < (half + 1) * (C / 2); ++c) {
                const float v = bf2f(rowp(sh, s, c)[e]);
                sm += v; sq += v * v;
            }
            scr[idx * 4 + half * 2 + 0] = sm;
            scr[idx * 4 + half * 2 + 1] = sq;
        }
    }
    __syncthreads();
    if (tid < ehi - elo) {
        const int e = elo + tid;
        const float sm = scr[tid * 4 + 0] + scr[tid * 4 + 2];
        const float sq = scr[tid * 4 + 1] + scr[tid * 4 + 3];
        const float mu = sm * (1.0f / C);
        const float va = sq * (1.0f / C) - mu * mu;
        mean[e] = mu;
        rstd[e] = rsqrtf(va + 1e-6f);
    }
    __syncthreads();
    const int lane = tid & 63, wv = tid >> 6;
    for (int j = 0; j < C / NWAVE; ++j) {
        const int o = rfl(wv + NWAVE * j);
        const float wo = W[o], bo = bias[o];
        u16* r = rowp(sh, s, o);
        for (int p = elo; p < ehi; p += 64) {
            const int e = p + lane;
            if (e < ehi) {
                const float v = (bf2f(r[e]) - mean[e]) * rstd[e] * wo + bo;
                const bool gv = (unsigned)(l0 + e) < 4096u;
                r[e] = gv ? f2bf(v) : (u16)0;
            }
        }
    }
}

// ---------------- LN1 stats straight from global x ---------------------------
DEVI void ln1_stats(const float* xg, int b, int l0, float* scr, float* mean, float* rstd) {
    const int tid = threadIdx.x;
    if (tid < 256) {
        const int idx = tid & 127, half = tid >> 7;
        if (idx < EXT) {
            float sm = 0.f, sq = 0.f;
            const int l = l0 + idx;
            if ((unsigned)l < 4096u) {
                const float* p = xg + ((size_t)b * 256 + half * 128) * 4096 + l;
                for (int c = 0; c < 128; ++c) {
                    const float v = p[(size_t)c * 4096];
                    sm += v; sq += v * v;
                }
            }
            scr[idx * 4 + half * 2 + 0] = sm;
            scr[idx * 4 + half * 2 + 1] = sq;
        }
    }
    __syncthreads();
    if (tid < EXT) {
        const float sm = scr[tid * 4 + 0] + scr[tid * 4 + 2];
        const float sq = scr[tid * 4 + 1] + scr[tid * 4 + 3];
        const float mu = sm * (1.0f / 256.0f);
        const float va = sq * (1.0f / 256.0f) - mu * mu;
        mean[tid] = mu;
        rstd[tid] = rsqrtf(va + 1e-6f);
    }
}

// ---------------- load 64-channel chunk of x, apply LN1, store bf16 ----------
DEVI void norm_load(u16* sh, int slot, const float* xg, int b, int cbase,
                    const float* lnw, const float* lnb,
                    const float* mean, const float* rstd,
                    int elo, int ehi, int l0) {
    const int lane = threadIdx.x & 63;
    const int wv   = threadIdx.x >> 6;
    for (int j = 0; j < 64 / NWAVE; ++j) {
        const int o = rfl(wv + NWAVE * j);
        const float* p = xg + ((size_t)b * 256 + cbase + o) * 4096;
        const float wo = lnw[cbase + o], bo = lnb[cbase + o];
        u16* r = sh + slot * SLOT + o * EXT;
        for (int pp = elo; pp < ehi; pp += 64) {
            const int e = pp + lane;
            if (e < ehi) {
                const int l = l0 + e;
                const bool gv = (unsigned)l < 4096u;
                float v = gv ? p[l] : 0.f;
                v = (v - mean[e]) * rstd[e] * wo + bo;
                r[e] = gv ? f2bf(v) : (u16)0;
            }
        }
    }
}

// ---------------- fused: dw3(dwin) + pw(pwin) -> LDS slot or global ----------
template<int CPW, bool TOG>
DEVI void dw3pw_ph(u16* sh, SL dwin, SL pwin, int outSlot,
                   float* outg, int b, int ochan,
                   const float* dwW, const float* dwB,
                   const float* pwW, const float* pwB,
                   int elo, int ehi, int l0) {
    const int lane = threadIdx.x & 63;
    const int wv   = threadIdx.x >> 6;
    for (int jb = 0; jb < 2; ++jb) {
        const int o0 = rfl(wv + NWAVE * (4 * jb + 0));
        const int o1 = rfl(wv + NWAVE * (4 * jb + 1));
        const int o2 = rfl(wv + NWAVE * (4 * jb + 2));
        const int o3 = rfl(wv + NWAVE * (4 * jb + 3));
        const u16* d0 = rowp(sh, dwin, o0);
        const u16* d1 = rowp(sh, dwin, o1);
        const u16* d2 = rowp(sh, dwin, o2);
        const u16* d3 = rowp(sh, dwin, o3);
        for (int p = elo; p < ehi; p += 64) {
            const int e = p + lane;
            if (e >= ehi) continue;
            float a0 = dwB[o0] + pwB[o0];
            float a1 = dwB[o1] + pwB[o1];
            float a2 = dwB[o2] + pwB[o2];
            float a3 = dwB[o3] + pwB[o3];
            #pragma unroll
            for (int k = 0; k < 3; ++k) {
                a0 = fmaf(dwW[o0 * 3 + k], bf2f(d0[e + k - 1]), a0);
                a1 = fmaf(dwW[o1 * 3 + k], bf2f(d1[e + k - 1]), a1);
                a2 = fmaf(dwW[o2 * 3 + k], bf2f(d2[e + k - 1]), a2);
                a3 = fmaf(dwW[o3 * 3 + k], bf2f(d3[e + k - 1]), a3);
            }
            for (int cb = 0; cb < CPW; cb += 64) {
                const u16* bp = rowp(sh, pwin, cb) + e;
                const float* q0 = pwW + o0 * CPW + cb;
                const float* q1 = pwW + o1 * CPW + cb;
                const float* q2 = pwW + o2 * CPW + cb;
                const float* q3 = pwW + o3 * CPW + cb;
                #pragma unroll 16
                for (int c2 = 0; c2 < 64; ++c2) {
                    const float xv = bf2f(bp[c2 * EXT]);
                    a0 = fmaf(q0[c2], xv, a0);
                    a1 = fmaf(q1[c2], xv, a1);
                    a2 = fmaf(q2[c2], xv, a2);
                    a3 = fmaf(q3[c2], xv, a3);
                }
            }
            if (TOG) {
                const size_t base = ((size_t)b * 256) * 4096 + (size_t)(l0 + e);
                outg[base + (size_t)(ochan + o0) * 4096] = a0;
                outg[base + (size_t)(ochan + o1) * 4096] = a1;
                outg[base + (size_t)(ochan + o2) * 4096] = a2;
                outg[base + (size_t)(ochan + o3) * 4096] = a3;
            } else {
                const bool gv = (unsigned)(l0 + e) < 4096u;
                u16* r0 = sh + outSlot * SLOT + o0 * EXT;
                u16* r1 = sh + outSlot * SLOT + o1 * EXT;
                u16* r2 = sh + outSlot * SLOT + o2 * EXT;
                u16* r3 = sh + outSlot * SLOT + o3 * EXT;
                r0[e] = gv ? f2bf(a0) : (u16)0;
                r1[e] = gv ? f2bf(a1) : (u16)0;
                r2[e] = gv ? f2bf(a2) : (u16)0;
                r3[e] = gv ? f2bf(a3) : (u16)0;
            }
        }
    }
}

// ---------------- pw 192x192 straight to global output -----------------------
DEVI void pw_glob(u16* sh, SL in, float* outg, int b, int ochan,
                  const float* W, const float* bias, int elo, int ehi, int l0) {
    const int lane = threadIdx.x & 63;
    const int wv   = threadIdx.x >> 6;
    for (int jb = 0; jb < 6; ++jb) {
        const int o0 = rfl(wv + NWAVE * (4 * jb + 0));
        const int o1 = rfl(wv + NWAVE * (4 * jb + 1));
        const int o2 = rfl(wv + NWAVE * (4 * jb + 2));
        const int o3 = rfl(wv + NWAVE * (4 * jb + 3));
        const float* w0 = W + o0 * 192;
        const float* w1 = W + o1 * 192;
        const float* w2 = W + o2 * 192;
        const float* w3 = W + o3 * 192;
        for (int p = elo; p < ehi; p += 64) {
            const int e = p + lane;
            if (e >= ehi) continue;
            float a0 = bias[o0], a1 = bias[o1], a2 = bias[o2], a3 = bias[o3];
            for (int cb = 0; cb < 192; cb += 64) {
                const u16* bp = rowp(sh, in, cb) + e;
                const float* q0 = w0 + cb;
                const float* q1 = w1 + cb;
                const float* q2 = w2 + cb;
                const float* q3 = w3 + cb;
                #pragma unroll 16
                for (int c2 = 0; c2 < 64; ++c2) {
                    const float xv = bf2f(bp[c2 * EXT]);
                    a0 = fmaf(q0[c2], xv, a0);
                    a1 = fmaf(q1[c2], xv, a1);
                    a2 = fmaf(q2[c2], xv, a2);
                    a3 = fmaf(q3[c2], xv, a3);
                }
            }
            const size_t base = ((size_t)b * 256) * 4096 + (size_t)(l0 + e);
            outg[base + (size_t)(ochan + o0) * 4096] = a0;
            outg[base + (size_t)(ochan + o1) * 4096] = a1;
            outg[base + (size_t)(ochan + o2) * 4096] = a2;
            outg[base + (size_t)(ochan + o3) * 4096] = a3;
        }
    }
}

// ============================================================================

struct KArgs { const float* p[47]; float* out; };

enum {
    I_X = 0, I_LN1W, I_LN1B, I_A1PW, I_A1PB, I_A1DW, I_A1DB, I_V1W, I_V1B,
    I_V11W, I_V11B, I_V12W, I_V12B, I_C31W, I_C31B,
    I_LN2W, I_LN2B, I_A2PW, I_A2PB, I_A2DW, I_A2DB, I_V2W, I_V2B,
    I_V21W, I_V21B, I_V22W, I_V22B, I_P2W, I_P2B, I_C32W, I_C32B,
    I_LN3W, I_LN3B, I_A3PW, I_A3PB, I_A3DW, I_A3DB, I_V3W, I_V3B,
    I_V31W, I_V31B, I_V32W, I_V32B, I_P3W, I_P3B, I_C33W, I_C33B
};

__global__ __launch_bounds__(512) void convmod_kernel(KArgs a) {
    __shared__ u16 pool[9 * SLOT];                       // 101376 B
    __shared__ float meanA[EXT], rstdA[EXT], meanB[EXT], rstdB[EXT];
    __shared__ float scr[512];

    const int b    = blockIdx.x >> 6;
    const int tile = blockIdx.x & 63;
    const int l0   = tile * 64 - 12;
    const float* xg = a.p[I_X];
    u16* sh = pool;

    // ---- LN1 stats + normalized chunks 0,1 ----
    ln1_stats(xg, b, l0, scr, meanA, rstdA);
    __syncthreads();
    norm_load(sh, 0, xg, b,  0, a.p[I_LN1W], a.p[I_LN1B], meanA, rstdA, 0, EXT, l0);
    norm_load(sh, 1, xg, b, 64, a.p[I_LN1W], a.p[I_LN1B], meanA, rstdA, 0, EXT, l0);
    __syncthreads();
    // ---- stage 1 ----
    pw_ph<64, 64, true >(sh, SL{0,-1,-1}, SL{2,-1,-1}, a.p[I_A1PW], a.p[I_A1PB], 0, 88, l0);   // g1
    __syncthreads();
    dw_ph<64, 7, 3, false>(sh, SL{2,-1,-1}, SL{3,-1,-1}, SL{0,0,0}, a.p[I_A1DW], a.p[I_A1DB], 3, 85, l0); // a1
    __syncthreads();
    pw_ph<64, 64, false>(sh, SL{0,-1,-1}, SL{4,-1,-1}, a.p[I_V1W], a.p[I_V1B], 3, 85, l0);     // pv1
    __syncthreads();
    mul_ph<64>(sh, SL{3,-1,-1}, SL{4,-1,-1}, 3, 85);                                            // t1
    __syncthreads();
    pw_ph<64, 64, false>(sh, SL{4,-1,-1}, SL{0,-1,-1}, a.p[I_V11W], a.p[I_V11B], 3, 85, l0);   // mul1
    __syncthreads();
    pw_ph<64, 64, false>(sh, SL{1,-1,-1}, SL{2,-1,-1}, a.p[I_V12W], a.p[I_V12B], 2, 86, l0);   // pwv12
    __syncthreads();
    dw_ph<64, 3, 1, true>(sh, SL{2,-1,-1}, SL{1,-1,-1}, SL{3,-1,-1}, a.p[I_C31W], a.p[I_C31B], 3, 85, l0); // x1low
    __syncthreads();
    ln_ph<128>(sh, SL{1,0,-1}, a.p[I_LN2W], a.p[I_LN2B], 3, 85, l0, scr, meanB, rstdB);        // x1ln
    __syncthreads();
    // ---- stage 2 ----
    pw_ph<128, 128, true >(sh, SL{1,0,-1}, SL{2,3,-1}, a.p[I_A2PW], a.p[I_A2PB], 3, 85, l0);   // g2
    __syncthreads();
    dw_ph<128, 9, 4, false>(sh, SL{2,3,-1}, SL{4,5,-1}, SL{0,0,0}, a.p[I_A2DW], a.p[I_A2DB], 7, 81, l0); // a2
    __syncthreads();
    norm_load(sh, 2, xg, b, 128, a.p[I_LN1W], a.p[I_LN1B], meanA, rstdA, 6, 82, l0);           // xs2n
    __syncthreads();
    pw_ph<64, 64, false>(sh, SL{2,-1,-1}, SL{3,-1,-1}, a.p[I_V22W], a.p[I_V22B], 6, 82, l0);   // pwv22
    __syncthreads();
    dw3pw_ph<128, false>(sh, SL{3,-1,-1}, SL{4,5,-1}, 6, nullptr, b, 0,
                         a.p[I_C32W], a.p[I_C32B], a.p[I_P2W], a.p[I_P2B], 7, 81, l0);         // x2low
    __syncthreads();
    pw_ph<128, 128, false>(sh, SL{1,0,-1}, SL{2,3,-1}, a.p[I_V2W], a.p[I_V2B], 7, 81, l0);     // pv2
    __syncthreads();
    mul_ph<128>(sh, SL{4,5,-1}, SL{2,3,-1}, 7, 81);                                             // t2
    __syncthreads();
    pw_ph<128, 128, false>(sh, SL{2,3,-1}, SL{0,1,-1}, a.p[I_V21W], a.p[I_V21B], 7, 81, l0);   // mul2
    __syncthreads();
    ln_ph<192>(sh, SL{6,0,1}, a.p[I_LN3W], a.p[I_LN3B], 7, 81, l0, scr, meanB, rstdB);         // x2ln
    __syncthreads();
    // ---- stage 3 ----
    pw_ph<192, 192, true >(sh, SL{6,0,1}, SL{2,3,4}, a.p[I_A3PW], a.p[I_A3PB], 7, 81, l0);     // g3
    __syncthreads();
    dw_ph<192, 11, 5, false>(sh, SL{2,3,4}, SL{2,3,4}, SL{0,0,0}, a.p[I_A3DW], a.p[I_A3DB], 12, 76, l0); // a3 (in place, single pass)
    __syncthreads();
    pw_ph<192, 192, false>(sh, SL{6,0,1}, SL{5,7,8}, a.p[I_V3W], a.p[I_V3B], 12, 76, l0);      // pv3
    __syncthreads();
    mul_ph<192>(sh, SL{2,3,4}, SL{5,7,8}, 12, 76);                                              // t3
    __syncthreads();
    pw_glob(sh, SL{5,7,8}, a.out, b, 64, a.p[I_V31W], a.p[I_V31B], 12, 76, l0);                // mul3 -> out[64:256]
    __syncthreads();
    norm_load(sh, 6, xg, b, 192, a.p[I_LN1W], a.p[I_LN1B], meanA, rstdA, 11, 77, l0);          // xs3n
    __syncthreads();
    pw_ph<64, 64, false>(sh, SL{6,-1,-1}, SL{0,-1,-1}, a.p[I_V32W], a.p[I_V32B], 11, 77, l0);  // pwv32
    __syncthreads();
    dw3pw_ph<192, true>(sh, SL{0,-1,-1}, SL{2,3,4}, 0, a.out, b, 0,
                        a.p[I_C33W], a.p[I_C33B], a.p[I_P3W], a.p[I_P3B], 12, 76, l0);         // x3 -> out[0:64]
}

extern "C" void kernel_launch(void* const* d_in, const int* in_sizes, int n_in,
                              void* d_out, int out_size, void* d_ws, size_t ws_size,
                              hipStream_t stream) {
    (void)in_sizes; (void)n_in; (void)out_size; (void)d_ws; (void)ws_size;
    KArgs a;
    for (int i = 0; i < 47; ++i) a.p[i] = (const float*)d_in[i];
    a.out = (float*)d_out;
    convmod_kernel<<<dim3(32 * 64), dim3(512), 0, stream>>>(a);
}

// Round 2
// 864.754 us; speedup vs baseline: 7.6831x; 7.6831x over previous
//
#include <hip/hip_runtime.h>
#include <cmath>

// ============================================================================
// ConvMod1D fused kernel — round 1: MFMA port.
// LDS layout: [pos][chan] bf16, row stride RS=72 u16 (64 chans + 8 pad).
// 9 slots of 88 rows -> 114 KB LDS, 1 block/CU, 512 threads (8 waves).
// Pointwise convs -> mfma_f32_16x16x32_bf16: A = W[o][c] (bf16 in d_ws,
// K-contiguous), B = X[pos][chan] (K-contiguous), C/D: col=lane&15 (pos),
// row=quad*4+reg (chan).  Wave grid: 4 M-splits x 2 N-splits (3 ntiles each).
// Depthwise / LN / mul / gating stay VALU (small FLOP share).
//
// Slot schedule (liveness checked phase-by-phase):
//  S0:xs0n->mul1->a3_hi  S1:xs1n->x1low->g3_0->pv3/t3_0->xs3n
//  S2:g1->pwv12->g2lo->xs2n->pv2/t2_lo->g3_1->pv3/t3_1->pwv32
//  S3:a1->g2hi->pwv22->pv2/t2_hi->g3_2->pv3/t3_2->x3pw
//  S4:pv1/t1->a2lo->mul2lo  S5:a2hi->mul2hi  S6:x2pw/x2low  S7,S8:a3_lo/mid
// ============================================================================

using u16 = unsigned short;
typedef short shrt8 __attribute__((ext_vector_type(8)));
typedef short shrt4 __attribute__((ext_vector_type(4)));
typedef float f32x4 __attribute__((ext_vector_type(4)));

#define DEVI __device__ __forceinline__

static constexpr int EXT  = 88;
static constexpr int RS   = 72;          // row stride (u16): 64 + 8 pad
static constexpr int SLOT = EXT * RS;    // 6336 u16 = 12672 B
static constexpr int NW   = 8;           // waves per block

DEVI u16 f2bf(float f) {                 // RNE fp32 -> bf16
    unsigned u = __float_as_uint(f);
    u += 0x7FFFu + ((u >> 16) & 1u);
    return (u16)(u >> 16);
}
DEVI float bf2f(u16 h) { return __uint_as_float(((unsigned)h) << 16); }
DEVI float gelu_f(float x) { return 0.5f * x * (1.0f + erff(x * 0.70710678118654752f)); }

struct SL { int a, b, c; };
DEVI int slotOf(SL s, int ch) { return ch < 64 ? s.a : (ch < 128 ? s.b : s.c); }

// ---------------- pointwise conv via MFMA ------------------------------------
// out[o][e] = sum_c W[o][c] X[c][e] + bias[o]; optional exact GELU; store to
// LDS slots (zero at global-invalid l) or straight to global fp32 (TOG).
template<int O, int C, bool GELU, bool TOG>
DEVI void pw_mfma(u16* sh, SL in, SL out, const u16* Wb, const float* bias,
                  int elo, int ehi, int l0, float* outg, int bidx, int ochan) {
    constexpr int MR = O / 64;           // mtiles per wave
    constexpr int KT = C / 32;
    const int lane = threadIdx.x & 63;
    const int wv   = threadIdx.x >> 6;
    const int mw = wv >> 1, nw = wv & 1;
    const int col  = lane & 15;
    const int quad = lane >> 4;
    const int mrow = mw * (MR * 16) + col;      // A row loaded by this lane
    const int kq   = quad * 8;                  // k offset inside 32-block
    const int crow = mw * (MR * 16) + quad * 4; // C/D row base

    f32x4 acc[MR][3];
    #pragma unroll
    for (int mi = 0; mi < MR; ++mi) {
        const f32x4 bv = *(const f32x4*)(bias + crow + mi * 16);
        acc[mi][0] = bv; acc[mi][1] = bv; acc[mi][2] = bv;
    }
    bool act[3]; int bpos[3];
    #pragma unroll
    for (int ni = 0; ni < 3; ++ni) {
        const int nt = nw * 3 + ni;
        act[ni] = (nt * 16 < ehi) && (nt * 16 + 16 > elo);
        int p = nt * 16 + col; if (p > 87) p = 87;   // clamp (masked cols only)
        bpos[ni] = p;
    }
    #pragma unroll
    for (int kt = 0; kt < KT; ++kt) {
        shrt8 af[MR];
        #pragma unroll
        for (int mi = 0; mi < MR; ++mi)
            af[mi] = *(const shrt8*)(Wb + (size_t)(mrow + mi * 16) * C + kt * 32 + kq);
        const int k0 = kt * 32;
        const u16* bs = sh + slotOf(in, k0) * SLOT + ((k0 & 63) + kq);
        #pragma unroll
        for (int ni = 0; ni < 3; ++ni) {
            if (!act[ni]) continue;
            const shrt8 bf = *(const shrt8*)(bs + bpos[ni] * RS);
            #pragma unroll
            for (int mi = 0; mi < MR; ++mi)
                acc[mi][ni] = __builtin_amdgcn_mfma_f32_16x16x32_bf16(af[mi], bf, acc[mi][ni], 0, 0, 0);
        }
    }
    #pragma unroll
    for (int ni = 0; ni < 3; ++ni) {
        if (!act[ni]) continue;
        const int e = (nw * 3 + ni) * 16 + col;
        if (e < elo || e >= ehi) continue;
        const int l = l0 + e;
        #pragma unroll
        for (int mi = 0; mi < MR; ++mi) {
            f32x4 v = acc[mi][ni];
            if (GELU) { v[0]=gelu_f(v[0]); v[1]=gelu_f(v[1]); v[2]=gelu_f(v[2]); v[3]=gelu_f(v[3]); }
            const int ch = crow + mi * 16;
            if (TOG) {
                float* og = outg + ((size_t)bidx * 256 + ochan + ch) * 4096 + l;
                og[0] = v[0]; og[4096] = v[1]; og[2*4096] = v[2]; og[3*4096] = v[3];
            } else {
                const bool gv = (unsigned)l < 4096u;
                shrt4 pk;
                pk[0] = gv ? (short)f2bf(v[0]) : (short)0;
                pk[1] = gv ? (short)f2bf(v[1]) : (short)0;
                pk[2] = gv ? (short)f2bf(v[2]) : (short)0;
                pk[3] = gv ? (short)f2bf(v[3]) : (short)0;
                *(shrt4*)(sh + slotOf(out, ch) * SLOT + e * RS + (ch & 63)) = pk;
            }
        }
    }
}

// ---------------- depthwise conv (VALU), chan-per-lane, 8-pos window ---------
// ADD: out[e][c] = dw(in)[e][c] + add[e][c]  (add==out in-place is safe)
template<int C, int K, int PAD, bool ADD>
DEVI void dw_ph(u16* sh, SL in, SL add, SL out, const float* W, const float* bias,
                int elo, int ehi, int l0) {
    const int lane = threadIdx.x & 63;
    const int wv   = threadIdx.x >> 6;
    const int nwin = (ehi - elo + 7) >> 3;
    const int tasks = (C / 64) * nwin;
    for (int t = wv; t < tasks; t += NW) {
        const int cb = t / nwin, wi = t - cb * nwin;
        const int c = cb * 64 + lane;
        float wk[K];
        #pragma unroll
        for (int k = 0; k < K; ++k) wk[k] = W[c * K + k];
        const float bo = bias[c];
        const int e0 = elo + wi * 8;
        const u16* si = sh + slotOf(in, c) * SLOT + lane;
        const u16* sa = ADD ? (sh + slotOf(add, c) * SLOT + lane) : nullptr;
        u16* so = sh + slotOf(out, c) * SLOT + lane;
        float r[K + 7];
        #pragma unroll
        for (int m = 0; m < K + 7; ++m) {
            int e = e0 - PAD + m; if (e > 87) e = 87;   // over-reads feed masked outputs only
            r[m] = bf2f(si[e * RS]);
        }
        #pragma unroll
        for (int j = 0; j < 8; ++j) {
            const int e = e0 + j;
            if (e >= ehi) break;
            float acc = bo;
            #pragma unroll
            for (int k = 0; k < K; ++k) acc = fmaf(wk[k], r[j + k], acc);
            if (ADD) acc += bf2f(sa[e * RS]);
            const bool gv = (unsigned)(l0 + e) < 4096u;
            so[e * RS] = gv ? f2bf(acc) : (u16)0;
        }
    }
}

// ---------------- elementwise io *= a ----------------------------------------
template<int C>
DEVI void mul_ph(u16* sh, SL a, SL io, int elo, int ehi) {
    const int tid = threadIdx.x;
    const int nC8 = C / 8;
    const int total = (ehi - elo) * nC8;
    for (int t = tid; t < total; t += 512) {
        const int e  = elo + t / nC8;
        const int c0 = (t - (t / nC8) * nC8) * 8;
        const u16* pa = sh + slotOf(a, c0) * SLOT + e * RS + (c0 & 63);
        u16*       pi = sh + slotOf(io, c0) * SLOT + e * RS + (c0 & 63);
        shrt8 va = *(const shrt8*)pa, vi = *(const shrt8*)pi, vo;
        #pragma unroll
        for (int i = 0; i < 8; ++i)
            vo[i] = (short)f2bf(bf2f((u16)vi[i]) * bf2f((u16)va[i]));
        *(shrt8*)pi = vo;
    }
}

// ---------------- LayerNorm over channels, in place --------------------------
template<int C>
DEVI void ln_ph(u16* sh, SL s, const float* W, const float* B,
                int elo, int ehi, int l0, float* scr, float* mean, float* rstd) {
    constexpr int P = C / 64;
    const int tid = threadIdx.x;
    const int nP = ehi - elo;
    if (tid < nP * P) {
        const int e = elo + tid / P;
        const int part = tid - (tid / P) * P;
        const u16* row = sh + slotOf(s, part * 64) * SLOT + e * RS;
        float sm = 0.f, sq = 0.f;
        #pragma unroll
        for (int j = 0; j < 8; ++j) {
            shrt8 v = *(const shrt8*)(row + j * 8);
            #pragma unroll
            for (int i = 0; i < 8; ++i) { float f = bf2f((u16)v[i]); sm += f; sq += f * f; }
        }
        scr[tid * 2] = sm; scr[tid * 2 + 1] = sq;
    }
    __syncthreads();
    if (tid < nP) {
        float sm = 0.f, sq = 0.f;
        for (int p = 0; p < P; ++p) { sm += scr[(tid * P + p) * 2]; sq += scr[(tid * P + p) * 2 + 1]; }
        const float mu = sm * (1.0f / C);
        const float va = sq * (1.0f / C) - mu * mu;
        mean[elo + tid] = mu; rstd[elo + tid] = rsqrtf(va + 1e-6f);
    }
    __syncthreads();
    const int nC8 = C / 8, total = nP * nC8;
    for (int t = tid; t < total; t += 512) {
        const int e  = elo + t / nC8;
        const int c0 = (t - (t / nC8) * nC8) * 8;
        const float mu = mean[e], rs = rstd[e];
        const bool gv = (unsigned)(l0 + e) < 4096u;
        u16* p = sh + slotOf(s, c0) * SLOT + e * RS + (c0 & 63);
        shrt8 v = *(const shrt8*)p, o;
        const f32x4 w0 = *(const f32x4*)(W + c0), w1 = *(const f32x4*)(W + c0 + 4);
        const f32x4 b0 = *(const f32x4*)(B + c0), b1 = *(const f32x4*)(B + c0 + 4);
        #pragma unroll
        for (int i = 0; i < 4; ++i) {
            float f = (bf2f((u16)v[i]) - mu) * rs * w0[i] + b0[i];
            o[i] = gv ? (short)f2bf(f) : (short)0;
        }
        #pragma unroll
        for (int i = 0; i < 4; ++i) {
            float f = (bf2f((u16)v[4 + i]) - mu) * rs * w1[i] + b1[i];
            o[4 + i] = gv ? (short)f2bf(f) : (short)0;
        }
        *(shrt8*)p = o;
    }
}

// ---------------- LN1 stats straight from global x ---------------------------
DEVI void ln1_stats(const float* xg, int b, int l0, float* scr, float* mean, float* rstd) {
    const int tid = threadIdx.x;
    if (tid < 256) {
        const int idx = tid & 127, half = tid >> 7;
        if (idx < EXT) {
            float sm = 0.f, sq = 0.f;
            const int l = l0 + idx;
            if ((unsigned)l < 4096u) {
                const float* p = xg + ((size_t)b * 256 + half * 128) * 4096 + l;
                for (int c = 0; c < 128; ++c) {
                    const float v = p[(size_t)c * 4096];
                    sm += v; sq += v * v;
                }
            }
            scr[idx * 4 + half * 2 + 0] = sm;
            scr[idx * 4 + half * 2 + 1] = sq;
        }
    }
    __syncthreads();
    if (tid < EXT) {
        const float sm = scr[tid * 4] + scr[tid * 4 + 2];
        const float sq = scr[tid * 4 + 1] + scr[tid * 4 + 3];
        const float mu = sm * (1.0f / 256.0f);
        const float va = sq * (1.0f / 256.0f) - mu * mu;
        mean[tid] = mu; rstd[tid] = rsqrtf(va + 1e-6f);
    }
}

// ---------------- load 64-chan chunk of x, apply LN1, store bf16 -------------
DEVI void norm_load(u16* sh, int slot, const float* xg, int b, int cbase,
                    const float* lnw, const float* lnb,
                    const float* mean, const float* rstd,
                    int elo, int ehi, int l0) {
    const int lane = threadIdx.x & 63;
    const int wv   = threadIdx.x >> 6;
    for (int j = 0; j < 8; ++j) {
        const int o = wv + NW * j;
        const float* p = xg + ((size_t)b * 256 + cbase + o) * 4096;
        const float wo = lnw[cbase + o], bo = lnb[cbase + o];
        u16* r = sh + slot * SLOT + o;
        for (int pp = elo; pp < ehi; pp += 64) {
            const int e = pp + lane;
            if (e < ehi) {
                const int l = l0 + e;
                const bool gv = (unsigned)l < 4096u;
                float v = gv ? p[l] : 0.f;
                v = (v - mean[e]) * rstd[e] * wo + bo;
                r[e * RS] = gv ? f2bf(v) : (u16)0;
            }
        }
    }
}

// ---------------- final dw3 + add -> global (coalesced along l) --------------
DEVI void dw3_glob(u16* sh, int inSlot, int addSlot, const float* W, const float* B,
                   float* outg, int b, int l0) {
    const int lane = threadIdx.x & 63;
    const int wv   = threadIdx.x >> 6;
    const int e = 12 + lane;
    const int l = l0 + e;                       // always in [0,4096)
    for (int j = 0; j < 8; ++j) {
        const int c = wv * 8 + j;
        const u16* si = sh + inSlot * SLOT + c;
        float acc = B[c];
        acc = fmaf(W[c * 3 + 0], bf2f(si[(e - 1) * RS]), acc);
        acc = fmaf(W[c * 3 + 1], bf2f(si[e * RS]), acc);
        acc = fmaf(W[c * 3 + 2], bf2f(si[(e + 1) * RS]), acc);
        acc += bf2f(sh[addSlot * SLOT + e * RS + c]);
        outg[((size_t)b * 256 + c) * 4096 + l] = acc;
    }
}

// ============================================================================

enum {
    I_X = 0, I_LN1W, I_LN1B, I_A1PW, I_A1PB, I_A1DW, I_A1DB, I_V1W, I_V1B,
    I_V11W, I_V11B, I_V12W, I_V12B, I_C31W, I_C31B,
    I_LN2W, I_LN2B, I_A2PW, I_A2PB, I_A2DW, I_A2DB, I_V2W, I_V2B,
    I_V21W, I_V21B, I_V22W, I_V22B, I_P2W, I_P2B, I_C32W, I_C32B,
    I_LN3W, I_LN3B, I_A3PW, I_A3PB, I_A3DW, I_A3DB, I_V3W, I_V3B,
    I_V31W, I_V31B, I_V32W, I_V32B, I_P3W, I_P3B, I_C33W, I_C33B
};
enum { W_A1P = 0, W_V1, W_V11, W_V12, W_A2P, W_V2, W_V21, W_V22, W_P2,
       W_A3P, W_V3, W_V31, W_V32, W_P3, W_N };

struct KArgs { const float* p[47]; const u16* w[W_N]; float* out; };
struct CvtArgs { const float* src[W_N]; u16* dst; int off[W_N + 1]; };

__global__ __launch_bounds__(256) void cvt_kernel(CvtArgs a) {
    const int i = blockIdx.x * 256 + threadIdx.x;
    if (i >= a.off[W_N]) return;
    int s = 0;
    while (i >= a.off[s + 1]) ++s;
    a.dst[i] = f2bf(a.src[s][i - a.off[s]]);
}

__global__ __launch_bounds__(512) void convmod_kernel(KArgs a) {
    __shared__ u16 pool[9 * SLOT];                       // 114048 B
    __shared__ float meanA[EXT], rstdA[EXT], meanB[EXT], rstdB[EXT];
    __shared__ float scr[512];

    const int b    = blockIdx.x >> 6;
    const int tile = blockIdx.x & 63;
    const int l0   = tile * 64 - 12;
    const float* xg = a.p[I_X];
    u16* sh = pool;

    ln1_stats(xg, b, l0, scr, meanA, rstdA);
    __syncthreads();
    norm_load(sh, 0, xg, b,  0, a.p[I_LN1W], a.p[I_LN1B], meanA, rstdA, 0, EXT, l0);
    norm_load(sh, 1, xg, b, 64, a.p[I_LN1W], a.p[I_LN1B], meanA, rstdA, 0, EXT, l0);
    __syncthreads();
    // ---- stage 1 ----
    pw_mfma<64, 64, true,  false>(sh, SL{0,-1,-1}, SL{2,-1,-1}, a.w[W_A1P], a.p[I_A1PB], 0, 88, l0, nullptr, b, 0);  // g1
    __syncthreads();
    dw_ph<64, 7, 3, false>(sh, SL{2,-1,-1}, SL{0,0,0}, SL{3,-1,-1}, a.p[I_A1DW], a.p[I_A1DB], 3, 85, l0);            // a1
    __syncthreads();
    pw_mfma<64, 64, false, false>(sh, SL{0,-1,-1}, SL{4,-1,-1}, a.w[W_V1], a.p[I_V1B], 3, 85, l0, nullptr, b, 0);    // pv1
    __syncthreads();
    mul_ph<64>(sh, SL{3,-1,-1}, SL{4,-1,-1}, 3, 85);                                                                  // t1
    __syncthreads();
    pw_mfma<64, 64, false, false>(sh, SL{4,-1,-1}, SL{0,-1,-1}, a.w[W_V11], a.p[I_V11B], 3, 85, l0, nullptr, b, 0);  // mul1
    __syncthreads();
    pw_mfma<64, 64, false, false>(sh, SL{1,-1,-1}, SL{2,-1,-1}, a.w[W_V12], a.p[I_V12B], 2, 86, l0, nullptr, b, 0);  // pwv12
    __syncthreads();
    dw_ph<64, 3, 1, true>(sh, SL{2,-1,-1}, SL{3,-1,-1}, SL{1,-1,-1}, a.p[I_C31W], a.p[I_C31B], 3, 85, l0);           // x1low
    __syncthreads();
    ln_ph<128>(sh, SL{1,0,-1}, a.p[I_LN2W], a.p[I_LN2B], 3, 85, l0, scr, meanB, rstdB);                              // x1ln
    __syncthreads();
    // ---- stage 2 ----
    pw_mfma<128, 128, true,  false>(sh, SL{1,0,-1}, SL{2,3,-1}, a.w[W_A2P], a.p[I_A2PB], 3, 85, l0, nullptr, b, 0);  // g2
    __syncthreads();
    dw_ph<128, 9, 4, false>(sh, SL{2,3,-1}, SL{0,0,0}, SL{4,5,-1}, a.p[I_A2DW], a.p[I_A2DB], 7, 81, l0);             // a2
    __syncthreads();
    norm_load(sh, 2, xg, b, 128, a.p[I_LN1W], a.p[I_LN1B], meanA, rstdA, 6, 82, l0);                                 // xs2n
    __syncthreads();
    pw_mfma<64, 64, false, false>(sh, SL{2,-1,-1}, SL{3,-1,-1}, a.w[W_V22], a.p[I_V22B], 6, 82, l0, nullptr, b, 0);  // pwv22
    __syncthreads();
    pw_mfma<64, 128, false, false>(sh, SL{4,5,-1}, SL{6,-1,-1}, a.w[W_P2], a.p[I_P2B], 7, 81, l0, nullptr, b, 0);    // pw(a2,p2)
    __syncthreads();
    dw_ph<64, 3, 1, true>(sh, SL{3,-1,-1}, SL{6,-1,-1}, SL{6,-1,-1}, a.p[I_C32W], a.p[I_C32B], 7, 81, l0);           // x2low (+=)
    __syncthreads();
    pw_mfma<128, 128, false, false>(sh, SL{1,0,-1}, SL{2,3,-1}, a.w[W_V2], a.p[I_V2B], 7, 81, l0, nullptr, b, 0);    // pv2
    __syncthreads();
    mul_ph<128>(sh, SL{4,5,-1}, SL{2,3,-1}, 7, 81);                                                                   // t2
    __syncthreads();
    pw_mfma<128, 128, false, false>(sh, SL{2,3,-1}, SL{4,5,-1}, a.w[W_V21], a.p[I_V21B], 7, 81, l0, nullptr, b, 0);  // mul2
    __syncthreads();
    ln_ph<192>(sh, SL{6,4,5}, a.p[I_LN3W], a.p[I_LN3B], 7, 81, l0, scr, meanB, rstdB);                               // x2ln
    __syncthreads();
    // ---- stage 3 ----
    pw_mfma<192, 192, true,  false>(sh, SL{6,4,5}, SL{1,2,3}, a.w[W_A3P], a.p[I_A3PB], 7, 81, l0, nullptr, b, 0);    // g3
    __syncthreads();
    dw_ph<192, 11, 5, false>(sh, SL{1,2,3}, SL{0,0,0}, SL{7,8,0}, a.p[I_A3DW], a.p[I_A3DB], 12, 76, l0);             // a3
    __syncthreads();
    pw_mfma<192, 192, false, false>(sh, SL{6,4,5}, SL{1,2,3}, a.w[W_V3], a.p[I_V3B], 12, 76, l0, nullptr, b, 0);     // pv3
    __syncthreads();
    mul_ph<192>(sh, SL{7,8,0}, SL{1,2,3}, 12, 76);                                                                    // t3
    __syncthreads();
    pw_mfma<192, 192, false, true>(sh, SL{1,2,3}, SL{-1,-1,-1}, a.w[W_V31], a.p[I_V31B], 12, 76, l0, a.out, b, 64);  // mul3 -> out
    __syncthreads();
    norm_load(sh, 1, xg, b, 192, a.p[I_LN1W], a.p[I_LN1B], meanA, rstdA, 11, 77, l0);                                // xs3n
    __syncthreads();
    pw_mfma<64, 64, false, false>(sh, SL{1,-1,-1}, SL{2,-1,-1}, a.w[W_V32], a.p[I_V32B], 11, 77, l0, nullptr, b, 0); // pwv32
    __syncthreads();
    pw_mfma<64, 192, false, false>(sh, SL{7,8,0}, SL{3,-1,-1}, a.w[W_P3], a.p[I_P3B], 12, 76, l0, nullptr, b, 0);    // pw(a3,p3)
    __syncthreads();
    dw3_glob(sh, 2, 3, a.p[I_C33W], a.p[I_C33B], a.out, b, l0);                                                      // x3 -> out
}

extern "C" void kernel_launch(void* const* d_in, const int* in_sizes, int n_in,
                              void* d_out, int out_size, void* d_ws, size_t ws_size,
                              hipStream_t stream) {
    (void)in_sizes; (void)n_in; (void)out_size; (void)ws_size;
    static const int widx[W_N] = { I_A1PW, I_V1W, I_V11W, I_V12W, I_A2PW, I_V2W,
                                   I_V21W, I_V22W, I_P2W, I_A3PW, I_V3W, I_V31W,
                                   I_V32W, I_P3W };
    static const int wsz[W_N]  = { 4096, 4096, 4096, 4096, 16384, 16384, 16384,
                                   4096, 8192, 36864, 36864, 36864, 4096, 12288 };
    CvtArgs ca; KArgs ka;
    int off = 0;
    for (int i = 0; i < W_N; ++i) {
        ca.src[i] = (const float*)d_in[widx[i]];
        ca.off[i] = off;
        off += wsz[i];
    }
    ca.off[W_N] = off;                       // 206848 elems = 413696 B in d_ws
    ca.dst = (u16*)d_ws;
    for (int i = 0; i < 47; ++i) ka.p[i] = (const float*)d_in[i];
    for (int i = 0; i < W_N; ++i) ka.w[i] = (const u16*)d_ws + ca.off[i];
    ka.out = (float*)d_out;

    cvt_kernel<<<dim3((off + 255) / 256), dim3(256), 0, stream>>>(ca);
    convmod_kernel<<<dim3(32 * 64), dim3(512), 0, stream>>>(ka);
}

// Round 3
// 857.004 us; speedup vs baseline: 7.7526x; 1.0090x over previous
//
#include <hip/hip_runtime.h>
#include <cmath>

// ============================================================================
// ConvMod1D fused kernel — round 2: occupancy + phase merging.
// TL=32 positions/block (halo 12 each side -> EXT=56). 9 LDS slots of
// [pos][chan] bf16, row stride RS=72 u16 -> 75.5 KB LDS => 2 blocks/CU,
// 16 waves/CU. Grid 32 batches x 128 tiles = 4096 blocks, 512 thr (8 waves).
// Pointwise convs -> mfma_f32_16x16x32_bf16 (A=W bf16 in d_ws, B=LDS rows,
// C/D: col=lane&15 -> pos, row=quad*4+reg -> chan). Wave grid 4M x 2N,
// NT=2 n-tiles/wave (4 n-tiles over 56 pos). GELU = A&S erf approx (1.5e-7).
//
// Phase / slot schedule (S0..S8, liveness checked):
//  sync ln1_stats | P0 xs0n->S0, xs1n->S1 | P1 g1->S2, pv1->S4, pwv12->S3
//  | P2 a1:S2->S5 | P3 t1:S5*S4->S4, x1low:dw3(S3)+S5->S1 | P4 mul1:S4->S0
//  | P5 ln2[S1,S0] | P6 g2->[S2,S3], pv2->[S4,S5], xs2n->S6
//  | P7 a2:[S2,S3]->[S7,S8], pwv22:S6->S0 | P8 t2:[S7,S8]*[S4,S5]->[S4,S5],
//    p2a:pw(a2)->S1 | P9 x2low:dw3(S0)+S1->S1, mul2:[S4,S5]->[S2,S3]
//  | P10 ln3[S1,S2,S3] | P11 g3->[S4,S5,S6], pv3->[S7,S8,S0]
//  | P12 a3:[S4,S5,S6]->[S1,S2,S3] | P13 t3:[S1..]*[S7,S8,S0]->[S7,S8,S0],
//    xs3n->S4 | P14 mul3:pw(t3)->OUT[64:256], p3a:pw(a3)->S5, pwv32:S4->S6
//  | P15 x3:dw3(S6)+S5->OUT[0:64]
// ============================================================================

using u16 = unsigned short;
typedef short shrt8 __attribute__((ext_vector_type(8)));
typedef short shrt4 __attribute__((ext_vector_type(4)));
typedef float f32x4 __attribute__((ext_vector_type(4)));

#define DEVI __device__ __forceinline__

static constexpr int EXT  = 56;          // 32 useful + 2*12 halo
static constexpr int RS   = 72;          // row stride in u16 (64 + 8 pad)
static constexpr int SLOT = EXT * RS;    // 4032 u16 = 8064 B
static constexpr int NW   = 8;

DEVI u16 f2bf(float f) {                 // RNE fp32 -> bf16
    unsigned u = __float_as_uint(f);
    u += 0x7FFFu + ((u >> 16) & 1u);
    return (u16)(u >> 16);
}
DEVI float bf2f(u16 h) { return __uint_as_float(((unsigned)h) << 16); }

// exact-GELU via Abramowitz-Stegun 7.1.26 erf (|err| <= 1.5e-7, branch-free)
DEVI float gelu_f(float x) {
    const float y  = x * 0.70710678118654752f;
    const float ay = fabsf(y);
    const float t  = __builtin_amdgcn_rcpf(fmaf(0.3275911f, ay, 1.0f));
    float p = 1.061405429f;
    p = fmaf(p, t, -1.453152027f);
    p = fmaf(p, t,  1.421413741f);
    p = fmaf(p, t, -0.284496736f);
    p = fmaf(p, t,  0.254829592f);
    float er = 1.0f - p * t * __expf(-ay * ay);
    er = copysignf(er, y);
    return 0.5f * x * (1.0f + er);
}

struct SL { int a, b, c; };
DEVI int slotOf(SL s, int ch) { return ch < 64 ? s.a : (ch < 128 ? s.b : s.c); }

// ---------------- pointwise conv via MFMA ------------------------------------
template<int O, int C, bool GELU, bool TOG>
DEVI void pw_mfma(u16* sh, SL in, SL out, const u16* Wb, const float* bias,
                  int elo, int ehi, int l0, float* outg, int bidx, int ochan) {
    constexpr int MR = O / 64;           // m-tiles per wave (4 m-splits)
    constexpr int KT = C / 32;
    const int lane = threadIdx.x & 63;
    const int wv   = threadIdx.x >> 6;
    const int mw = wv >> 1, nw = wv & 1;
    const int col  = lane & 15;
    const int quad = lane >> 4;
    const int mrow = mw * (MR * 16) + col;
    const int kq   = quad * 8;
    const int crow = mw * (MR * 16) + quad * 4;

    f32x4 acc[MR][2];
    #pragma unroll
    for (int mi = 0; mi < MR; ++mi) {
        const f32x4 bv = *(const f32x4*)(bias + crow + mi * 16);
        acc[mi][0] = bv; acc[mi][1] = bv;
    }
    bool act[2]; int bpos[2];
    #pragma unroll
    for (int ni = 0; ni < 2; ++ni) {
        const int nt = nw * 2 + ni;
        act[ni] = (nt * 16 < ehi) && (nt * 16 + 16 > elo);
        int p = nt * 16 + col; if (p > EXT - 1) p = EXT - 1;  // masked cols only
        bpos[ni] = p;
    }
    #pragma unroll
    for (int kt = 0; kt < KT; ++kt) {
        shrt8 af[MR];
        #pragma unroll
        for (int mi = 0; mi < MR; ++mi)
            af[mi] = *(const shrt8*)(Wb + (size_t)(mrow + mi * 16) * C + kt * 32 + kq);
        const int k0 = kt * 32;
        const u16* bs = sh + slotOf(in, k0) * SLOT + ((k0 & 63) + kq);
        #pragma unroll
        for (int ni = 0; ni < 2; ++ni) {
            if (!act[ni]) continue;
            const shrt8 bf = *(const shrt8*)(bs + bpos[ni] * RS);
            #pragma unroll
            for (int mi = 0; mi < MR; ++mi)
                acc[mi][ni] = __builtin_amdgcn_mfma_f32_16x16x32_bf16(af[mi], bf, acc[mi][ni], 0, 0, 0);
        }
    }
    #pragma unroll
    for (int ni = 0; ni < 2; ++ni) {
        if (!act[ni]) continue;
        const int e = (nw * 2 + ni) * 16 + col;
        if (e < elo || e >= ehi) continue;
        const int l = l0 + e;
        #pragma unroll
        for (int mi = 0; mi < MR; ++mi) {
            f32x4 v = acc[mi][ni];
            if (GELU) { v[0]=gelu_f(v[0]); v[1]=gelu_f(v[1]); v[2]=gelu_f(v[2]); v[3]=gelu_f(v[3]); }
            const int ch = crow + mi * 16;
            if (TOG) {
                float* og = outg + ((size_t)bidx * 256 + ochan + ch) * 4096 + l;
                og[0] = v[0]; og[4096] = v[1]; og[2*4096] = v[2]; og[3*4096] = v[3];
            } else {
                const bool gv = (unsigned)l < 4096u;
                shrt4 pk;
                pk[0] = gv ? (short)f2bf(v[0]) : (short)0;
                pk[1] = gv ? (short)f2bf(v[1]) : (short)0;
                pk[2] = gv ? (short)f2bf(v[2]) : (short)0;
                pk[3] = gv ? (short)f2bf(v[3]) : (short)0;
                *(shrt4*)(sh + slotOf(out, ch) * SLOT + e * RS + (ch & 63)) = pk;
            }
        }
    }
}

// ---------------- depthwise conv (VALU), chan-per-lane, 8-pos windows --------
template<int C, int K, int PAD, bool ADD>
DEVI void dw_ph(u16* sh, SL in, SL add, SL out, const float* W, const float* bias,
                int elo, int ehi, int l0) {
    const int lane = threadIdx.x & 63;
    const int wv   = threadIdx.x >> 6;
    const int nwin = (ehi - elo + 7) >> 3;
    const int tasks = (C / 64) * nwin;
    for (int t = wv; t < tasks; t += NW) {
        const int cb = t / nwin, wi = t - cb * nwin;
        const int c = cb * 64 + lane;
        float wk[K];
        #pragma unroll
        for (int k = 0; k < K; ++k) wk[k] = W[c * K + k];
        const float bo = bias[c];
        const int e0 = elo + wi * 8;
        const u16* si = sh + slotOf(in, c) * SLOT + lane;
        const u16* sa = ADD ? (sh + slotOf(add, c) * SLOT + lane) : nullptr;
        u16* so = sh + slotOf(out, c) * SLOT + lane;
        float r[K + 7];
        #pragma unroll
        for (int m = 0; m < K + 7; ++m) {
            int e = e0 - PAD + m; if (e > EXT - 1) e = EXT - 1;  // feeds masked outputs only
            r[m] = bf2f(si[e * RS]);
        }
        #pragma unroll
        for (int j = 0; j < 8; ++j) {
            const int e = e0 + j;
            if (e >= ehi) break;
            float acc = bo;
            #pragma unroll
            for (int k = 0; k < K; ++k) acc = fmaf(wk[k], r[j + k], acc);
            if (ADD) acc += bf2f(sa[e * RS]);
            const bool gv = (unsigned)(l0 + e) < 4096u;
            so[e * RS] = gv ? f2bf(acc) : (u16)0;
        }
    }
}

// ---------------- elementwise io *= a ----------------------------------------
template<int C>
DEVI void mul_ph(u16* sh, SL a, SL io, int elo, int ehi) {
    const int tid = threadIdx.x;
    const int nC8 = C / 8;
    const int total = (ehi - elo) * nC8;
    for (int t = tid; t < total; t += 512) {
        const int e  = elo + t / nC8;
        const int c0 = (t - (t / nC8) * nC8) * 8;
        const u16* pa = sh + slotOf(a, c0) * SLOT + e * RS + (c0 & 63);
        u16*       pi = sh + slotOf(io, c0) * SLOT + e * RS + (c0 & 63);
        shrt8 va = *(const shrt8*)pa, vi = *(const shrt8*)pi, vo;
        #pragma unroll
        for (int i = 0; i < 8; ++i)
            vo[i] = (short)f2bf(bf2f((u16)vi[i]) * bf2f((u16)va[i]));
        *(shrt8*)pi = vo;
    }
}

// ---------------- LayerNorm over channels, in place --------------------------
template<int C>
DEVI void ln_ph(u16* sh, SL s, const float* W, const float* B,
                int elo, int ehi, int l0, float* scr, float* mean, float* rstd) {
    constexpr int P = C / 64;
    const int tid = threadIdx.x;
    const int nP = ehi - elo;
    if (tid < nP * P) {
        const int e = elo + tid / P;
        const int part = tid - (tid / P) * P;
        const u16* row = sh + slotOf(s, part * 64) * SLOT + e * RS;
        float sm = 0.f, sq = 0.f;
        #pragma unroll
        for (int j = 0; j < 8; ++j) {
            shrt8 v = *(const shrt8*)(row + j * 8);
            #pragma unroll
            for (int i = 0; i < 8; ++i) { float f = bf2f((u16)v[i]); sm += f; sq += f * f; }
        }
        scr[tid * 2] = sm; scr[tid * 2 + 1] = sq;
    }
    __syncthreads();
    if (tid < nP) {
        float sm = 0.f, sq = 0.f;
        for (int p = 0; p < P; ++p) { sm += scr[(tid * P + p) * 2]; sq += scr[(tid * P + p) * 2 + 1]; }
        const float mu = sm * (1.0f / C);
        const float va = sq * (1.0f / C) - mu * mu;
        mean[elo + tid] = mu; rstd[elo + tid] = rsqrtf(va + 1e-6f);
    }
    __syncthreads();
    const int nC8 = C / 8, total = nP * nC8;
    for (int t = tid; t < total; t += 512) {
        const int e  = elo + t / nC8;
        const int c0 = (t - (t / nC8) * nC8) * 8;
        const float mu = mean[e], rs = rstd[e];
        const bool gv = (unsigned)(l0 + e) < 4096u;
        u16* p = sh + slotOf(s, c0) * SLOT + e * RS + (c0 & 63);
        shrt8 v = *(const shrt8*)p, o;
        const f32x4 w0 = *(const f32x4*)(W + c0), w1 = *(const f32x4*)(W + c0 + 4);
        const f32x4 b0 = *(const f32x4*)(B + c0), b1 = *(const f32x4*)(B + c0 + 4);
        #pragma unroll
        for (int i = 0; i < 4; ++i) {
            float f = (bf2f((u16)v[i]) - mu) * rs * w0[i] + b0[i];
            o[i] = gv ? (short)f2bf(f) : (short)0;
        }
        #pragma unroll
        for (int i = 0; i < 4; ++i) {
            float f = (bf2f((u16)v[4 + i]) - mu) * rs * w1[i] + b1[i];
            o[4 + i] = gv ? (short)f2bf(f) : (short)0;
        }
        *(shrt8*)p = o;
    }
}

// ---------------- LN1 stats straight from global x ---------------------------
DEVI void ln1_stats(const float* xg, int b, int l0, float* scr, float* mean, float* rstd) {
    const int tid = threadIdx.x;
    if (tid < 256) {
        const int idx = tid & 127, half = tid >> 7;
        if (idx < EXT) {
            float sm = 0.f, sq = 0.f;
            const int l = l0 + idx;
            if ((unsigned)l < 4096u) {
                const float* p = xg + ((size_t)b * 256 + half * 128) * 4096 + l;
                for (int c = 0; c < 128; ++c) {
                    const float v = p[(size_t)c * 4096];
                    sm += v; sq += v * v;
                }
            }
            scr[idx * 4 + half * 2 + 0] = sm;
            scr[idx * 4 + half * 2 + 1] = sq;
        }
    }
    __syncthreads();
    if (tid < EXT) {
        const float sm = scr[tid * 4] + scr[tid * 4 + 2];
        const float sq = scr[tid * 4 + 1] + scr[tid * 4 + 3];
        const float mu = sm * (1.0f / 256.0f);
        const float va = sq * (1.0f / 256.0f) - mu * mu;
        mean[tid] = mu; rstd[tid] = rsqrtf(va + 1e-6f);
    }
}

// ---------------- load 64-chan chunk of x, apply LN1, store bf16 -------------
DEVI void norm_load(u16* sh, int slot, const float* xg, int b, int cbase,
                    const float* lnw, const float* lnb,
                    const float* mean, const float* rstd,
                    int elo, int ehi, int l0) {
    const int lane = threadIdx.x & 63;
    const int wv   = threadIdx.x >> 6;
    for (int j = 0; j < 8; ++j) {
        const int o = wv + NW * j;
        const float* p = xg + ((size_t)b * 256 + cbase + o) * 4096;
        const float wo = lnw[cbase + o], bo = lnb[cbase + o];
        u16* r = sh + slot * SLOT + o;
        const int e = elo + lane;
        if (e < ehi) {
            const int l = l0 + e;
            const bool gv = (unsigned)l < 4096u;
            float v = gv ? p[l] : 0.f;
            v = (v - mean[e]) * rstd[e] * wo + bo;
            r[e * RS] = gv ? f2bf(v) : (u16)0;
        }
    }
}

// ---------------- final dw3 + add -> global (coalesced along l) --------------
DEVI void dw3_glob(u16* sh, int inSlot, int addSlot, const float* W, const float* B,
                   float* outg, int b, int l0) {
    const int tid = threadIdx.x;
    #pragma unroll
    for (int k = 0; k < 4; ++k) {
        const int idx = tid + k * 512;          // 2048 = 64 chans x 32 pos
        const int c   = idx >> 5;
        const int e   = 12 + (idx & 31);
        const u16* si = sh + inSlot * SLOT + c;
        float acc = B[c];
        acc = fmaf(W[c * 3 + 0], bf2f(si[(e - 1) * RS]), acc);
        acc = fmaf(W[c * 3 + 1], bf2f(si[e * RS]), acc);
        acc = fmaf(W[c * 3 + 2], bf2f(si[(e + 1) * RS]), acc);
        acc += bf2f(sh[addSlot * SLOT + e * RS + c]);
        outg[((size_t)b * 256 + c) * 4096 + (l0 + e)] = acc;
    }
}

// ============================================================================

enum {
    I_X = 0, I_LN1W, I_LN1B, I_A1PW, I_A1PB, I_A1DW, I_A1DB, I_V1W, I_V1B,
    I_V11W, I_V11B, I_V12W, I_V12B, I_C31W, I_C31B,
    I_LN2W, I_LN2B, I_A2PW, I_A2PB, I_A2DW, I_A2DB, I_V2W, I_V2B,
    I_V21W, I_V21B, I_V22W, I_V22B, I_P2W, I_P2B, I_C32W, I_C32B,
    I_LN3W, I_LN3B, I_A3PW, I_A3PB, I_A3DW, I_A3DB, I_V3W, I_V3B,
    I_V31W, I_V31B, I_V32W, I_V32B, I_P3W, I_P3B, I_C33W, I_C33B
};
enum { W_A1P = 0, W_V1, W_V11, W_V12, W_A2P, W_V2, W_V21, W_V22, W_P2,
       W_A3P, W_V3, W_V31, W_V32, W_P3, W_N };

struct KArgs { const float* p[47]; const u16* w[W_N]; float* out; };
struct CvtArgs { const float* src[W_N]; u16* dst; int off[W_N + 1]; };

__global__ __launch_bounds__(256) void cvt_kernel(CvtArgs a) {
    const int i = blockIdx.x * 256 + threadIdx.x;
    if (i >= a.off[W_N]) return;
    int s = 0;
    while (i >= a.off[s + 1]) ++s;
    a.dst[i] = f2bf(a.src[s][i - a.off[s]]);
}

__global__ __launch_bounds__(512, 4) void convmod_kernel(KArgs a) {
    __shared__ u16 pool[9 * SLOT];                       // 72576 B
    __shared__ float meanA[EXT], rstdA[EXT], meanB[EXT], rstdB[EXT];
    __shared__ float scr[512];

    const int b    = blockIdx.x >> 7;
    const int tile = blockIdx.x & 127;
    const int l0   = tile * 32 - 12;
    const float* xg = a.p[I_X];
    u16* sh = pool;

    ln1_stats(xg, b, l0, scr, meanA, rstdA);
    __syncthreads();
    // P0
    norm_load(sh, 0, xg, b,  0, a.p[I_LN1W], a.p[I_LN1B], meanA, rstdA, 0, EXT, l0);
    norm_load(sh, 1, xg, b, 64, a.p[I_LN1W], a.p[I_LN1B], meanA, rstdA, 0, EXT, l0);
    __syncthreads();
    // P1: g1, pv1, pwv12
    pw_mfma<64, 64, true,  false>(sh, SL{0,-1,-1}, SL{2,-1,-1}, a.w[W_A1P], a.p[I_A1PB], 0, 56, l0, nullptr, b, 0);
    pw_mfma<64, 64, false, false>(sh, SL{0,-1,-1}, SL{4,-1,-1}, a.w[W_V1],  a.p[I_V1B],  3, 53, l0, nullptr, b, 0);
    pw_mfma<64, 64, false, false>(sh, SL{1,-1,-1}, SL{3,-1,-1}, a.w[W_V12], a.p[I_V12B], 2, 54, l0, nullptr, b, 0);
    __syncthreads();
    // P2: a1
    dw_ph<64, 7, 3, false>(sh, SL{2,-1,-1}, SL{0,0,0}, SL{5,-1,-1}, a.p[I_A1DW], a.p[I_A1DB], 3, 53, l0);
    __syncthreads();
    // P3: t1, x1low
    mul_ph<64>(sh, SL{5,-1,-1}, SL{4,-1,-1}, 3, 53);
    dw_ph<64, 3, 1, true>(sh, SL{3,-1,-1}, SL{5,-1,-1}, SL{1,-1,-1}, a.p[I_C31W], a.p[I_C31B], 3, 53, l0);
    __syncthreads();
    // P4: mul1
    pw_mfma<64, 64, false, false>(sh, SL{4,-1,-1}, SL{0,-1,-1}, a.w[W_V11], a.p[I_V11B], 3, 53, l0, nullptr, b, 0);
    __syncthreads();
    // P5: ln2 over [S1,S0]
    ln_ph<128>(sh, SL{1,0,-1}, a.p[I_LN2W], a.p[I_LN2B], 3, 53, l0, scr, meanB, rstdB);
    __syncthreads();
    // P6: g2, pv2, xs2n
    norm_load(sh, 6, xg, b, 128, a.p[I_LN1W], a.p[I_LN1B], meanA, rstdA, 6, 50, l0);
    pw_mfma<128, 128, true,  false>(sh, SL{1,0,-1}, SL{2,3,-1}, a.w[W_A2P], a.p[I_A2PB], 3, 53, l0, nullptr, b, 0);
    pw_mfma<128, 128, false, false>(sh, SL{1,0,-1}, SL{4,5,-1}, a.w[W_V2],  a.p[I_V2B],  7, 49, l0, nullptr, b, 0);
    __syncthreads();
    // P7: a2, pwv22
    dw_ph<128, 9, 4, false>(sh, SL{2,3,-1}, SL{0,0,0}, SL{7,8,-1}, a.p[I_A2DW], a.p[I_A2DB], 7, 49, l0);
    pw_mfma<64, 64, false, false>(sh, SL{6,-1,-1}, SL{0,-1,-1}, a.w[W_V22], a.p[I_V22B], 6, 50, l0, nullptr, b, 0);
    __syncthreads();
    // P8: t2, p2a
    mul_ph<128>(sh, SL{7,8,-1}, SL{4,5,-1}, 7, 49);
    pw_mfma<64, 128, false, false>(sh, SL{7,8,-1}, SL{1,-1,-1}, a.w[W_P2], a.p[I_P2B], 7, 49, l0, nullptr, b, 0);
    __syncthreads();
    // P9: x2low (+= p2a, in place on S1), mul2
    dw_ph<64, 3, 1, true>(sh, SL{0,-1,-1}, SL{1,-1,-1}, SL{1,-1,-1}, a.p[I_C32W], a.p[I_C32B], 7, 49, l0);
    pw_mfma<128, 128, false, false>(sh, SL{4,5,-1}, SL{2,3,-1}, a.w[W_V21], a.p[I_V21B], 7, 49, l0, nullptr, b, 0);
    __syncthreads();
    // P10: ln3 over [S1,S2,S3]
    ln_ph<192>(sh, SL{1,2,3}, a.p[I_LN3W], a.p[I_LN3B], 7, 49, l0, scr, meanB, rstdB);
    __syncthreads();
    // P11: g3, pv3
    pw_mfma<192, 192, true,  false>(sh, SL{1,2,3}, SL{4,5,6}, a.w[W_A3P], a.p[I_A3PB], 7, 49, l0, nullptr, b, 0);
    pw_mfma<192, 192, false, false>(sh, SL{1,2,3}, SL{7,8,0}, a.w[W_V3],  a.p[I_V3B],  12, 44, l0, nullptr, b, 0);
    __syncthreads();
    // P12: a3
    dw_ph<192, 11, 5, false>(sh, SL{4,5,6}, SL{0,0,0}, SL{1,2,3}, a.p[I_A3DW], a.p[I_A3DB], 12, 44, l0);
    __syncthreads();
    // P13: t3 (in place on [S7,S8,S0]), xs3n
    mul_ph<192>(sh, SL{1,2,3}, SL{7,8,0}, 12, 44);
    norm_load(sh, 4, xg, b, 192, a.p[I_LN1W], a.p[I_LN1B], meanA, rstdA, 11, 45, l0);
    __syncthreads();
    // P14: mul3 -> out[64:256], p3a -> S5, pwv32 -> S6
    pw_mfma<192, 192, false, true >(sh, SL{7,8,0}, SL{-1,-1,-1}, a.w[W_V31], a.p[I_V31B], 12, 44, l0, a.out, b, 64);
    pw_mfma<64, 192, false, false>(sh, SL{1,2,3}, SL{5,-1,-1}, a.w[W_P3],  a.p[I_P3B],  12, 44, l0, nullptr, b, 0);
    pw_mfma<64, 64,  false, false>(sh, SL{4,-1,-1}, SL{6,-1,-1}, a.w[W_V32], a.p[I_V32B], 11, 45, l0, nullptr, b, 0);
    __syncthreads();
    // P15: x3 -> out[0:64]
    dw3_glob(sh, 6, 5, a.p[I_C33W], a.p[I_C33B], a.out, b, l0);
}

extern "C" void kernel_launch(void* const* d_in, const int* in_sizes, int n_in,
                              void* d_out, int out_size, void* d_ws, size_t ws_size,
                              hipStream_t stream) {
    (void)in_sizes; (void)n_in; (void)out_size; (void)ws_size;
    static const int widx[W_N] = { I_A1PW, I_V1W, I_V11W, I_V12W, I_A2PW, I_V2W,
                                   I_V21W, I_V22W, I_P2W, I_A3PW, I_V3W, I_V31W,
                                   I_V32W, I_P3W };
    static const int wsz[W_N]  = { 4096, 4096, 4096, 4096, 16384, 16384, 16384,
                                   4096, 8192, 36864, 36864, 36864, 4096, 12288 };
    CvtArgs ca; KArgs ka;
    int off = 0;
    for (int i = 0; i < W_N; ++i) {
        ca.src[i] = (const float*)d_in[widx[i]];
        ca.off[i] = off;
        off += wsz[i];
    }
    ca.off[W_N] = off;                       // 206848 elems = 413696 B in d_ws
    ca.dst = (u16*)d_ws;
    for (int i = 0; i < 47; ++i) ka.p[i] = (const float*)d_in[i];
    for (int i = 0; i < W_N; ++i) ka.w[i] = (const u16*)d_ws + ca.off[i];
    ka.out = (float*)d_out;

    cvt_kernel<<<dim3((off + 255) / 256), dim3(256), 0, stream>>>(ca);
    convmod_kernel<<<dim3(32 * 128), dim3(512), 0, stream>>>(ka);
}